// Round 6
// baseline (284.226 us; speedup 1.0000x reference)
//
#include <hip/hip_runtime.h>

typedef unsigned short u16;
typedef __bf16 bf16x8 __attribute__((ext_vector_type(8)));
typedef float f32x4 __attribute__((ext_vector_type(4)));

__device__ __forceinline__ u16 f2b(float f) {
    unsigned u = __builtin_bit_cast(unsigned, f);
    unsigned r = (u + 0x7fffu + ((u >> 16) & 1u)) >> 16;
    return (u16)r;
}
#if __has_builtin(__builtin_amdgcn_cvt_pk_bf16_f32)
typedef __bf16 bf16x2_t __attribute__((ext_vector_type(2)));
__device__ __forceinline__ unsigned pk2(float a, float b) {
    return __builtin_bit_cast(unsigned, __builtin_amdgcn_cvt_pk_bf16_f32(a, b));
}
#else
__device__ __forceinline__ unsigned pk2(float a, float b) {
    return (unsigned)f2b(a) | ((unsigned)f2b(b) << 16);
}
#endif
#if __has_builtin(__builtin_amdgcn_exp2f)
#define EXP2F(x) __builtin_amdgcn_exp2f(x)
#else
#define EXP2F(x) exp2f(x)
#endif

// async global->LDS 16B/lane; lds dest is wave-uniform base (+lane*16 by HW)
__device__ __forceinline__ void gl_lds16(const u16* g, u16* l) {
    __builtin_amdgcn_global_load_lds(
        (const __attribute__((address_space(1))) unsigned*)(const void*)g,
        (__attribute__((address_space(3))) unsigned*)(void*)l, 16, 0, 0);
}

// ---------------- convert x (fp32 -> bf16), 8 elems/thread ----------------
__global__ __launch_bounds__(256) void k_convert(const float* __restrict__ in,
                                                 u16* __restrict__ out, int n8) {
    int i = blockIdx.x * 256 + threadIdx.x;
    if (i >= n8) return;
    const float4* p = (const float4*)(in + (size_t)i * 8);
    float4 a = p[0], b = p[1];
    u16 t[8] = {f2b(a.x), f2b(a.y), f2b(a.z), f2b(a.w),
                f2b(b.x), f2b(b.y), f2b(b.z), f2b(b.w)};
    *(uint4*)(out + (size_t)i * 8) = *(const uint4*)t;
}

// -------- transpose + convert: in[R][C] fp32 -> out[C][R] bf16, 64x64 tiles --------
__global__ __launch_bounds__(256) void k_transpose_bf16(const float* __restrict__ in,
                                                        u16* __restrict__ out,
                                                        int R, int C) {
    __shared__ u16 tile[64][72];
    int tc = blockIdx.x * 64;
    int tr = blockIdx.y * 64;
    for (int i = threadIdx.x; i < 4096; i += 256) {
        int r = i >> 6, c = i & 63;
        tile[c][r] = f2b(in[(size_t)(tr + r) * C + tc + c]);
    }
    __syncthreads();
    for (int i = threadIdx.x; i < 4096; i += 256) {
        int r = i >> 6, c = i & 63;
        out[(size_t)(tc + r) * R + tr + c] = tile[r][c];
    }
}

// --- 128x128xK bf16 MFMA mainloop, BK=32, DOUBLE-BUFFERED global_load_lds ---
// One barrier per iter: at barrier, the DMA drained (vmcnt(0) auto-inserted)
// is the one issued a full compute-phase ago -> drain is ~free. DMA for tile
// k+1 issues right after the barrier, overlapping the compute on tile k.
// LDS: 2 buffers x 128x32 u16 per operand (32 KB total), unpadded (DMA order).
__device__ __forceinline__ void gemm_mainloop(const u16* __restrict__ Ab,
                                              const u16* __restrict__ Bb, int K,
                                              u16* As, u16* Bs, int tid,
                                              f32x4 (&acc)[4][4]) {
    const int wave = tid >> 6, lane = tid & 63;
    const int col = lane & 15, quad = lane >> 4;
    const int wm = wave >> 1, wn = wave & 1;
    const int lrow = lane >> 2, lk = (lane & 3) * 8;
    const int wofs = wave * 512;  // wave*16 rows * 32 cols
    const u16* gA0 = Ab + (size_t)(wave * 16 + lrow) * K + lk;
    const u16* gA1 = gA0 + (size_t)64 * K;
    const u16* gB0 = Bb + (size_t)(wave * 16 + lrow) * K + lk;
    const u16* gB1 = gB0 + (size_t)64 * K;
    // prologue: stage k=0 into buffer 0
    gl_lds16(gA0, As + wofs);
    gl_lds16(gA1, As + 2048 + wofs);
    gl_lds16(gB0, Bs + wofs);
    gl_lds16(gB1, Bs + 2048 + wofs);
    for (int k0 = 0; k0 < K; k0 += 32) {
        const int cb = ((k0 >> 5) & 1) * 4096;  // current buffer offset (u16)
        __syncthreads();  // drains vmcnt(0): deposit(cb) complete; prev reads of other buf done
        int kn = k0 + 32;
        if (kn < K) {
            const int nb = 4096 - cb;
            gl_lds16(gA0 + kn, As + nb + wofs);
            gl_lds16(gA1 + kn, As + nb + 2048 + wofs);
            gl_lds16(gB0 + kn, Bs + nb + wofs);
            gl_lds16(gB1 + kn, Bs + nb + 2048 + wofs);
        }
        bf16x8 af[4], bfr[4];
#pragma unroll
        for (int mt = 0; mt < 4; ++mt)
            af[mt] = *(const bf16x8*)(As + cb + (wm * 64 + mt * 16 + col) * 32 + quad * 8);
#pragma unroll
        for (int nt = 0; nt < 4; ++nt)
            bfr[nt] = *(const bf16x8*)(Bs + cb + (wn * 64 + nt * 16 + col) * 32 + quad * 8);
#pragma unroll
        for (int mt = 0; mt < 4; ++mt)
#pragma unroll
            for (int nt = 0; nt < 4; ++nt)
                acc[mt][nt] = __builtin_amdgcn_mfma_f32_16x16x32_bf16(
                    af[mt], bfr[nt], acc[mt][nt], 0, 0, 0);
    }
}

// ---------------- QKV GEMM + bias + RoPE + head reshape ----------------
// Q additionally prescaled by 0.125*log2(e) so attention softmax is pure exp2.
__global__ __launch_bounds__(256) void k_gemm_qkv_rope(
    const u16* __restrict__ A, const u16* __restrict__ Bt,
    const float* __restrict__ bias, u16* __restrict__ Qr, u16* __restrict__ Kr,
    u16* __restrict__ Vt) {
    __shared__ __align__(16) u16 As[2 * 128 * 32];
    __shared__ __align__(16) u16 Bs[2 * 128 * 32];
    const int K = 1024;
    int tid = threadIdx.x;
    int lane = tid & 63, wave = tid >> 6;
    int col = lane & 15, quad = lane >> 4;
    int wm = wave >> 1, wn = wave & 1;
    int mBase = blockIdx.y * 128;
    int nBase = blockIdx.x * 128;
    f32x4 acc[4][4] = {};
    gemm_mainloop(A + (size_t)mBase * K, Bt + (size_t)nBase * K, K, As, Bs, tid, acc);

    int n64 = nBase + wn * 64;
    int region = n64 >> 10;  // 0=q, 1=k, 2=v
    int h = (n64 & 1023) >> 6;
    if (region < 2) {
        u16* out = (region == 0) ? Qr : Kr;
        float qs = (region == 0) ? 0.18033688011112042f : 1.0f;  // 0.125*log2(e)
        const float C0 = 0.4152410118609203f;                    // log2(10000)/32
#pragma unroll
        for (int nt = 0; nt < 2; ++nt) {
            int d1 = nt * 16 + col;
            float inv_freq = exp2f(-C0 * (float)d1);
            float b1 = bias[n64 + nt * 16 + col];
            float b2 = bias[n64 + nt * 16 + col + 32];
#pragma unroll
            for (int mt = 0; mt < 4; ++mt) {
                int mrow = mBase + wm * 64 + mt * 16 + quad * 4;
#pragma unroll
                for (int r = 0; r < 4; ++r) {
                    int m = mrow + r;
                    int s = m & 2047, b = m >> 11;
                    float sn, cs;
                    __sincosf((float)s * inv_freq, &sn, &cs);
                    float t1 = acc[mt][nt][r] + b1;
                    float t2 = acc[mt][nt + 2][r] + b2;
                    size_t base = ((size_t)((b * 16 + h) * 2048 + s)) * 64;
                    out[base + d1] = f2b((t1 * cs - t2 * sn) * qs);
                    out[base + d1 + 32] = f2b((t2 * cs + t1 * sn) * qs);
                }
            }
        }
    } else {
#pragma unroll
        for (int nt = 0; nt < 4; ++nt) {
            int d = nt * 16 + col;
            float bv = bias[n64 + nt * 16 + col];
#pragma unroll
            for (int mt = 0; mt < 4; ++mt) {
                int mrow = mBase + wm * 64 + mt * 16 + quad * 4;
#pragma unroll
                for (int r = 0; r < 4; ++r) {
                    int m = mrow + r;
                    int s = m & 2047, b = m >> 11;
                    Vt[((size_t)((b * 16 + h) * 64 + d)) * 2048 + s] =
                        f2b(acc[mt][nt][r] + bv);
                }
            }
        }
    }
}

// ------------- flash attention (causal, transposed, permuted-row, 128q/block) -------------
// Block covers 128 queries = two 64-q tiles t0=2qb, t1=2qb+1; wave owns 16-q
// subtiles at q=qb*128+w*16 (sub0) and +64 (sub1). K/V frags read from LDS once
// per iter, reused by both subtiles. Staging is software-pipelined: global K/V
// loads for iter j+1 issue right after the staging barrier of iter j (register
// prefetch), hiding HBM/L2 latency behind compute. qb paired bx<->15-bx.
// Permuted-row QK^T: tile nt reads Ks row (nt&1)*32+(col>>2)*8+(nt>>1)*4+(col&3)
// so lane reg (nt,r) holds key (nt&1)*32+quad*8+(nt>>1)*4+r => PV B-frag is
// lane-local: {P4[2kk],P4[2kk+1],P4[2kk+4],P4[2kk+5]}. Fixed-max softmax.
__global__ __launch_bounds__(256) void k_attn(const u16* __restrict__ Qr,
                                              const u16* __restrict__ Kr,
                                              const u16* __restrict__ Vt,
                                              u16* __restrict__ O) {
    __shared__ __align__(16) u16 Ks[64 * 72];  // [key][d]
    __shared__ __align__(16) u16 Vs[64 * 72];  // [d][key]
    int tid = threadIdx.x, wave = tid >> 6, lane = tid & 63;
    int col = lane & 15, quad = lane >> 4;
    int bx = blockIdx.x, bh = blockIdx.y;
    int b = bh >> 4, h = bh & 15;
    size_t headQ = (size_t)bh * 2048 * 64;
    size_t headV = (size_t)bh * 64 * 2048;
    int r0 = tid >> 3, kc = tid & 7;
    int rb72 = ((col >> 2) * 8 + (col & 3)) * 72;  // permuted row base
    const u16* kgB = Kr + headQ + (size_t)r0 * 64 + kc * 8;
    const u16* vgB = Vt + headV + (size_t)r0 * 2048 + kc * 8;

    for (int half = 0; half < 2; ++half) {
        int qb = half ? bx : (15 - bx);
        int t0 = 2 * qb, t1 = t0 + 1;
        int myq0 = qb * 128 + wave * 16 + col;
        int myq1 = myq0 + 64;
        const u16* qp0 = Qr + headQ + (size_t)myq0 * 64;
        const u16* qp1 = Qr + headQ + (size_t)myq1 * 64;
        bf16x8 aq00 = *(const bf16x8*)(qp0 + quad * 8);
        bf16x8 aq01 = *(const bf16x8*)(qp0 + 32 + quad * 8);
        bf16x8 aq10 = *(const bf16x8*)(qp1 + quad * 8);
        bf16x8 aq11 = *(const bf16x8*)(qp1 + 32 + quad * 8);
        f32x4 o0[4] = {}, o1[4] = {};
        float l0 = 0.f, l1 = 0.f;

        // prefetch iter j=0
        uint4 pk0 = *(const uint4*)(kgB);
        uint4 pk1 = *(const uint4*)(kgB + (size_t)32 * 64);
        uint4 pv0 = *(const uint4*)(vgB);
        uint4 pv1 = *(const uint4*)(vgB + (size_t)32 * 2048);

        for (int j = 0; j <= t1; ++j) {
            bool d0 = (j <= t0);  // block-uniform
            __syncthreads();      // all waves done reading previous tile
            *(uint4*)(Ks + r0 * 72 + kc * 8) = pk0;
            *(uint4*)(Ks + (r0 + 32) * 72 + kc * 8) = pk1;
            *(uint4*)(Vs + r0 * 72 + kc * 8) = pv0;
            *(uint4*)(Vs + (r0 + 32) * 72 + kc * 8) = pv1;
            __syncthreads();
            {   // prefetch iter j+1 (clamped; overlaps compute below)
                int j2 = (j < t1) ? (j + 1) : t1;
                const u16* kg = kgB + (size_t)(j2 * 64) * 64;
                const u16* vg = vgB + (size_t)(j2 * 64);
                pk0 = *(const uint4*)kg;
                pk1 = *(const uint4*)(kg + (size_t)32 * 64);
                pv0 = *(const uint4*)vg;
                pv1 = *(const uint4*)(vg + (size_t)32 * 2048);
            }
            f32x4 s0[4], s1[4];
#pragma unroll
            for (int nt = 0; nt < 4; ++nt) {
                const u16* kp = Ks + rb72 + ((nt & 1) * 32 + (nt >> 1) * 4) * 72;
                bf16x8 ak0 = *(const bf16x8*)(kp + quad * 8);
                bf16x8 ak1 = *(const bf16x8*)(kp + 32 + quad * 8);
                if (d0) {
                    f32x4 z = {};
                    z = __builtin_amdgcn_mfma_f32_16x16x32_bf16(ak0, aq00, z, 0, 0, 0);
                    s0[nt] = __builtin_amdgcn_mfma_f32_16x16x32_bf16(ak1, aq01, z, 0, 0, 0);
                }
                f32x4 z = {};
                z = __builtin_amdgcn_mfma_f32_16x16x32_bf16(ak0, aq10, z, 0, 0, 0);
                s1[nt] = __builtin_amdgcn_mfma_f32_16x16x32_bf16(ak1, aq11, z, 0, 0, 0);
            }
            if (j == t0) {  // diagonal for sub0
#pragma unroll
                for (int nt = 0; nt < 4; ++nt) {
                    int keyb = j * 64 + (nt & 1) * 32 + quad * 8 + (nt >> 1) * 4;
#pragma unroll
                    for (int r = 0; r < 4; ++r)
                        if (keyb + r > myq0) s0[nt][r] = -3.0e38f;
                }
            }
            if (j == t1) {  // diagonal for sub1
#pragma unroll
                for (int nt = 0; nt < 4; ++nt) {
                    int keyb = j * 64 + (nt & 1) * 32 + quad * 8 + (nt >> 1) * 4;
#pragma unroll
                    for (int r = 0; r < 4; ++r)
                        if (keyb + r > myq1) s1[nt][r] = -3.0e38f;
                }
            }
            unsigned P40[8], P41[8];
            if (d0) {
#pragma unroll
                for (int nt = 0; nt < 4; ++nt) {
                    float p0 = EXP2F(s0[nt][0]);
                    float p1 = EXP2F(s0[nt][1]);
                    float p2 = EXP2F(s0[nt][2]);
                    float p3 = EXP2F(s0[nt][3]);
                    l0 += (p0 + p1) + (p2 + p3);
                    P40[2 * nt] = pk2(p0, p1);
                    P40[2 * nt + 1] = pk2(p2, p3);
                }
            }
#pragma unroll
            for (int nt = 0; nt < 4; ++nt) {
                float p0 = EXP2F(s1[nt][0]);
                float p1 = EXP2F(s1[nt][1]);
                float p2 = EXP2F(s1[nt][2]);
                float p3 = EXP2F(s1[nt][3]);
                l1 += (p0 + p1) + (p2 + p3);
                P41[2 * nt] = pk2(p0, p1);
                P41[2 * nt + 1] = pk2(p2, p3);
            }
#pragma unroll
            for (int kk = 0; kk < 2; ++kk) {
                uint4 bw0, bw1;
                bw0.x = P40[2 * kk];
                bw0.y = P40[2 * kk + 1];
                bw0.z = P40[2 * kk + 4];
                bw0.w = P40[2 * kk + 5];
                bw1.x = P41[2 * kk];
                bw1.y = P41[2 * kk + 1];
                bw1.z = P41[2 * kk + 4];
                bw1.w = P41[2 * kk + 5];
                bf16x8 bp0 = __builtin_bit_cast(bf16x8, bw0);
                bf16x8 bp1 = __builtin_bit_cast(bf16x8, bw1);
#pragma unroll
                for (int mt = 0; mt < 4; ++mt) {
                    bf16x8 av = *(const bf16x8*)(Vs + (mt * 16 + col) * 72 + kk * 32 + quad * 8);
                    if (d0)
                        o0[mt] = __builtin_amdgcn_mfma_f32_16x16x32_bf16(av, bp0, o0[mt], 0, 0, 0);
                    o1[mt] = __builtin_amdgcn_mfma_f32_16x16x32_bf16(av, bp1, o1[mt], 0, 0, 0);
                }
            }
        }
        l0 += __shfl_xor(l0, 16);
        l0 += __shfl_xor(l0, 32);
        l1 += __shfl_xor(l1, 16);
        l1 += __shfl_xor(l1, 32);
        float inv0 = 1.0f / l0, inv1 = 1.0f / l1;
        u16* orow0 = O + (size_t)(b * 2048 + myq0) * 1024 + h * 64;
        u16* orow1 = O + (size_t)(b * 2048 + myq1) * 1024 + h * 64;
#pragma unroll
        for (int mt = 0; mt < 4; ++mt) {
            uint2 w0, w1;
            w0.x = pk2(o0[mt][0] * inv0, o0[mt][1] * inv0);
            w0.y = pk2(o0[mt][2] * inv0, o0[mt][3] * inv0);
            w1.x = pk2(o1[mt][0] * inv1, o1[mt][1] * inv1);
            w1.y = pk2(o1[mt][2] * inv1, o1[mt][3] * inv1);
            *(uint2*)(orow0 + mt * 16 + quad * 4) = w0;
            *(uint2*)(orow1 + mt * 16 + quad * 4) = w1;
        }
    }
}

// ---------------- output projection GEMM ----------------
__global__ __launch_bounds__(256) void k_gemm_proj(const u16* __restrict__ A,
                                                   const u16* __restrict__ Bt,
                                                   const float* __restrict__ bias,
                                                   float* __restrict__ out) {
    __shared__ __align__(16) u16 As[2 * 128 * 32];
    __shared__ __align__(16) u16 Bs[2 * 128 * 32];
    const int K = 1024;
    int tid = threadIdx.x;
    int lane = tid & 63, wave = tid >> 6;
    int col = lane & 15, quad = lane >> 4;
    int wm = wave >> 1, wn = wave & 1;
    int mBase = blockIdx.y * 128;
    int nBase = blockIdx.x * 128;
    f32x4 acc[4][4] = {};
    gemm_mainloop(A + (size_t)mBase * K, Bt + (size_t)nBase * K, K, As, Bs, tid, acc);
#pragma unroll
    for (int nt = 0; nt < 4; ++nt) {
        int n = nBase + wn * 64 + nt * 16 + col;
        float bv = bias[n];
#pragma unroll
        for (int mt = 0; mt < 4; ++mt) {
            int m = mBase + wm * 64 + mt * 16 + quad * 4;
#pragma unroll
            for (int r = 0; r < 4; ++r)
                out[(size_t)(m + r) * 1024 + n] = acc[mt][nt][r] + bv;
        }
    }
}

// ---------------- launch ----------------
// ws: x_bf@0 (16MB) wqkvT (6MB) wprojT (2MB) Qr Kr Vt AO (16MB each)
extern "C" void kernel_launch(void* const* d_in, const int* in_sizes, int n_in,
                              void* d_out, int out_size, void* d_ws, size_t ws_size,
                              hipStream_t stream) {
    const float* x = (const float*)d_in[0];
    const float* w_qkv = (const float*)d_in[1];
    const float* b_qkv = (const float*)d_in[2];
    const float* w_proj = (const float*)d_in[3];
    const float* b_proj = (const float*)d_in[4];
    float* out = (float*)d_out;
    char* ws = (char*)d_ws;
    u16* x_bf = (u16*)(ws);
    u16* wqkvT = (u16*)(ws + 16777216);
    u16* wprojT = (u16*)(ws + 23068672);
    u16* Qr = (u16*)(ws + 25165824);
    u16* Kr = (u16*)(ws + 41943040);
    u16* Vt = (u16*)(ws + 58720256);
    u16* AO = (u16*)(ws + 75497472);

    k_convert<<<4096, 256, 0, stream>>>(x, x_bf, 1048576);
    k_transpose_bf16<<<dim3(48, 16), 256, 0, stream>>>(w_qkv, wqkvT, 1024, 3072);
    k_transpose_bf16<<<dim3(16, 16), 256, 0, stream>>>(w_proj, wprojT, 1024, 1024);
    k_gemm_qkv_rope<<<dim3(24, 64), 256, 0, stream>>>(x_bf, wqkvT, b_qkv, Qr, Kr, Vt);
    k_attn<<<dim3(8, 64), 256, 0, stream>>>(Qr, Kr, Vt, AO);
    k_gemm_proj<<<dim3(8, 64), 256, 0, stream>>>(AO, wprojT, b_proj, out);
}